// Round 12
// baseline (447.609 us; speedup 1.0000x reference)
//
#include <hip/hip_runtime.h>

// residualBlock: two sparse 3x3x3 convs (gather-GEMM over 27 offsets), ReLU
// between, residual add. bf16 MFMA.
//
// R18 = R17's A-tile-in-LDS idea, COUNT-FREE sync. R17 failed (absmax 0.219
// ~= one stale k-tile). Layout math re-verified correct; suspects were (a)
// counted vmcnt(9) -- breaks if the compiler emits ANY extra vmem (spills!),
// (b) divergent LDS dst pointer to global_load_lds (UB; must be uniform),
// (c) unmasked gathers (~6x TA work, R9). Fixes:
//  - 3-slot A ring, distance-2: tile kk staged at step kk-2. For s=0,1 the
//    stage was in the PREVIOUS chunk -> the chunk barrier's vmcnt(0) drain
//    guarantees it (spill-proof). Only s==2 (tile staged at s=0 same chunk)
//    needs a wait: plain vmcnt(0) BEFORE this step's stage issue.
//  - LDS dst = wave-uniform base (hardware adds lane*16).
//  - masked glds (16% lanes active) + 8x ds_write_b128 pre-zero of the slot
//    (hidden under MFMAs; lgkmcnt(0) fences zero-commit before glds issue).
//    Sentinel rows therefore stay exact zeros, bit-identical to R12.
// LDS 49,152 (W dbuf) + 98,304 (A ring 3x4x8KB) = 147,456 -> 1 block/CU.
// R8/R13: wave count irrelevant; in-flight gather bytes are the lever
// (R12 ~8KB/CU -> R18 ~64KB/CU staged >=2 steps ahead).
//
// Journal: R7 88.5 | R8 K-split 2.6x worse | R9 unmasked +9us | R10 reg-dbuf
// spill | R11 B-from-global 173us | R12 glds W-dbuf 77.3 BEST | R13 M-split
// 81 | R14/R15 setprio spills | R16 == R12 (275.0 total) | R17 LDS-A counted
// vmcnt: CORRECTNESS FAIL. R18: if correct but conv >= 80us -> revert R16,
// declare roofline (latency-under-load equilibrium confirmed at 8x depth).

#define N_ROWS 262144
#define HCH    64
#define KOFF   27
#define CHUNK  3

typedef unsigned short u16;
typedef __attribute__((ext_vector_type(8))) short short8;   // 8 bf16 (4 VGPRs)
typedef __attribute__((ext_vector_type(4))) float f32x4;    // 4 fp32 acc

__device__ __forceinline__ u16 f2bf(float f) {
    unsigned u = __builtin_bit_cast(unsigned, f);
    unsigned r = (u + 0x7FFFu + ((u >> 16) & 1u)) >> 16;   // RNE
    return (u16)r;
}
__device__ __forceinline__ float bf2f(u16 h) {
    return __builtin_bit_cast(float, (unsigned)h << 16);
}
__device__ __forceinline__ unsigned pack2(float a, float b) {
    return (unsigned)f2bf(a) | ((unsigned)f2bf(b) << 16);
}

// ------------------------------------------------------------------ prep ----
// One fused dispatch: [0,8193) prep_x ; [8193,9057) prep_w ; [9057,10081) nbrT
__global__ void prep_all(const float* __restrict__ x, u16* __restrict__ xb,
                         u16* __restrict__ yb,
                         const float* __restrict__ Wa, const float* __restrict__ Wb,
                         u16* __restrict__ Wta, u16* __restrict__ Wtb,
                         const int* __restrict__ nbr, int* __restrict__ nbrT) {
    const int b = blockIdx.x;
    if (b < 8193) {
        long gid = (long)b * 256 + threadIdx.x;             // 8-elem chunks
        const long total = (long)N_ROWS * HCH / 8;          // 2,097,152
        if (gid < total) {
            const float4* s = (const float4*)(x + gid * 8);
            float4 a = s[0], c = s[1];
            uint4 v;
            v.x = pack2(a.x, a.y); v.y = pack2(a.z, a.w);
            v.z = pack2(c.x, c.y); v.w = pack2(c.z, c.w);
            *(uint4*)(xb + gid * 8) = v;
        } else if (gid < total + HCH / 8) {                 // zero row N
            long c = gid - total;
            uint4 z; z.x = 0; z.y = 0; z.z = 0; z.w = 0;
            *(uint4*)(xb + (long)N_ROWS * HCH + c * 8) = z;
            *(uint4*)(yb + (long)N_ROWS * HCH + c * 8) = z;
        }
    } else if (b < 9057) {
        int gid = (b - 8193) * 256 + threadIdx.x;
        const int total = KOFF * HCH * HCH;                 // 110592
        const float* src; u16* dst; int e;
        if (gid < total)          { src = Wa; dst = Wta; e = gid; }
        else if (gid < 2 * total) { src = Wb; dst = Wtb; e = gid - total; }
        else return;
        int k = e >> 12, i = (e >> 6) & 63, j = e & 63;
        dst[(k << 12) + (j << 6) + i] = f2bf(src[e]);
    } else {
        // nbr transpose, 256 rows/block
        __shared__ int t[256 * 27];
        const int rowbase = (b - 9057) * 256;
        for (int e = threadIdx.x; e < 256 * 27; e += 256)
            t[e] = nbr[(size_t)rowbase * KOFF + e];
        __syncthreads();
        for (int e = threadIdx.x; e < 256 * 27; e += 256) {
            int k = e >> 8, r = e & 255;
            nbrT[(size_t)k * N_ROWS + rowbase + r] = t[r * KOFF + k];
        }
    }
}

// ------------------------------------------------------------------ conv ----
template <bool FIRST>
__global__ __launch_bounds__(256, 1) void conv_kernel(
    const u16* __restrict__ xg,      // gathered-from features, (N+1) x 64 bf16
    const u16* __restrict__ Wt,      // [27][64][64] bf16, [k][j][i]
    const int* __restrict__ nb,      // nbrT[27][N]
    u16* __restrict__ ybf,           // FIRST: relu output bf16
    float* __restrict__ outf,        // !FIRST: final fp32 output
    const u16* __restrict__ residb)  // !FIRST: residual x (bf16)
{
    __shared__ uint4 Wlds4[2 * CHUNK * 512];                // 49,152 B W dbuf
    __shared__ uint4 Alds[3][4][512];                       // 98,304 B A ring
    float* Fsh = (float*)Wlds4;                             // epilogue alias

    const int tid  = threadIdx.x;
    const int wave = tid >> 6;
    const int lane = tid & 63;
    const int m    = lane & 15;      // A row / B col / C col
    const int q    = lane >> 4;      // K-subgroup
    const int base = blockIdx.x * 256 + wave * 64;          // wave's 64 rows

    // A staging geometry: glds #g covers rows 8g..8g+7. Lane serves row
    // 8g+(lane>>3); its GLOBAL source chunk is (lane&7)^(lane>>3) (XOR
    // pre-swizzle) so the hardware's linear LDS write (uniform base +
    // lane*16) lands LDS[r][slot] = src[r][slot ^ (r&7)].
    const int coffE = (((lane & 7) ^ (lane >> 3)) << 3);    // element offset
    const int rsub  = lane >> 3;                            // row-in-group

    // W staging (proven in R12): swizzled GLOBAL source, linear LDS dst
    auto stageW = [&](int c, int bufSel) {
        const char* gbase = (const char*)(Wt + (size_t)c * CHUNK * 4096);
        uint4* bufBase = Wlds4 + bufSel * (CHUNK * 512);
#pragma unroll
        for (int i = 0; i < 6; i++) {
            int p = i * 256 + wave * 64 + lane;
            int e = (p & ~7) | ((p & 7) ^ ((p >> 3) & 7));
            const unsigned* src = (const unsigned*)(gbase + (size_t)e * 16);
            unsigned* dst = (unsigned*)(bufBase + i * 256 + wave * 64);
            __builtin_amdgcn_global_load_lds(
                (const __attribute__((address_space(1))) unsigned*)src,
                (__attribute__((address_space(3))) unsigned*)dst,
                16, 0, 0);
        }
    };

    // A staging: pre-zero the 8KB slot (8 ds_write_b128/lane), fence, then
    // exec-masked glds for non-sentinel rows only. LDS dst is WAVE-UNIFORM
    // (lane-invariant expression) -- valid even under divergence.
    auto stageA = [&](int slot, int iv) {
        uint4* Ab4 = &Alds[slot][wave][0];
        uint4 z; z.x = 0; z.y = 0; z.z = 0; z.w = 0;
#pragma unroll
        for (int i = 0; i < 8; i++) Ab4[i * 64 + lane] = z;
        asm volatile("s_waitcnt lgkmcnt(0)" ::: "memory");  // zeros committed
        char* Ab = (char*)Ab4;
#pragma unroll
        for (int g = 0; g < 8; g++) {
            int idxr = __shfl(iv, g * 8 + rsub, 64);
            if (idxr != N_ROWS) {
                const u16* src = xg + (size_t)idxr * HCH + coffE;
                unsigned* dst = (unsigned*)(Ab + g * 1024);  // uniform base
                __builtin_amdgcn_global_load_lds(
                    (const __attribute__((address_space(1))) unsigned*)src,
                    (__attribute__((address_space(3))) unsigned*)dst,
                    16, 0, 0);
            }
        }
    };

    f32x4 acc[4][4];
#pragma unroll
    for (int t = 0; t < 4; t++)
#pragma unroll
        for (int jt = 0; jt < 4; jt++)
            acc[t][jt] = (f32x4){0.f, 0.f, 0.f, 0.f};

    // ---- prologue: W(0) + tiles 0,1 staged; barrier lands everything ----
    stageW(0, 0);
    int iv0 = nb[base + lane];
    int iv1 = nb[(size_t)1 * N_ROWS + base + lane];
    int ivP[2];
    ivP[0] = nb[(size_t)2 * N_ROWS + base + lane];          // tile 2 (step 0)
    ivP[1] = nb[(size_t)3 * N_ROWS + base + lane];          // tile 3 (step 1)
    stageA(0, iv0);
    stageA(1, iv1);
    __syncthreads();                                        // vmcnt(0) drain

#pragma unroll
    for (int c = 0; c < KOFF / CHUNK; c++) {
        const int wbuf = c & 1;
        if (c + 1 < KOFF / CHUNK) stageW(c + 1, wbuf ^ 1);

        const u16* WshC = (const u16*)(Wlds4 + wbuf * (CHUNK * 512));
#pragma unroll
        for (int s = 0; s < CHUNK; s++) {
            const int kk = c * CHUNK + s;

            // s==2: tile kk was staged at s==0 of THIS chunk -- no barrier
            // since. Plain vmcnt(0) (spill-proof, count-free). s==0/1 tiles
            // were staged last chunk -> chunk barrier already drained them.
            if (s == 2) asm volatile("s_waitcnt vmcnt(0)" ::: "memory");

            // stage tile kk+2 into slot (kk+2)%3 (holds consumed tile kk-1)
            if (kk + 2 < KOFF) {
                stageA((kk + 2) % 3, ivP[kk & 1]);
                const int k4 = (kk + 4 < KOFF) ? kk + 4 : KOFF - 1;
                ivP[kk & 1] = nb[(size_t)k4 * N_ROWS + base + lane];
            }

            // B frags from swizzled W LDS (conflict-free b128)
            const u16* bs = WshC + s * 4096;
            short8 B0[4], B1[4];
#pragma unroll
            for (int jt = 0; jt < 4; jt++) {
                int j = jt * 16 + m;
                B0[jt] = *(const short8*)(bs + j * 64 + ((q    ) ^ (m & 7)) * 8);
                B1[jt] = *(const short8*)(bs + j * 64 + ((q + 4) ^ (m & 7)) * 8);
            }

            // A frags from swizzled LDS ring slot kk%3
            const u16* Ar = (const u16*)&Alds[kk % 3][wave][0];
            short8 A0[4], A1[4];
#pragma unroll
            for (int t = 0; t < 4; t++) {
                int r = t * 16 + m;
                A0[t] = *(const short8*)(Ar + r * 64 + ((q       ^ (r & 7)) << 3));
                A1[t] = *(const short8*)(Ar + r * 64 + (((q + 4) ^ (r & 7)) << 3));
            }

            // 32 MFMAs: all h0, then all h1
#pragma unroll
            for (int t = 0; t < 4; t++)
#pragma unroll
                for (int jt = 0; jt < 4; jt++)
                    acc[t][jt] = __builtin_amdgcn_mfma_f32_16x16x32_bf16(
                        A0[t], B0[jt], acc[t][jt], 0, 0, 0);
#pragma unroll
            for (int t = 0; t < 4; t++)
#pragma unroll
                for (int jt = 0; jt < 4; jt++)
                    acc[t][jt] = __builtin_amdgcn_mfma_f32_16x16x32_bf16(
                        A1[t], B1[jt], acc[t][jt], 0, 0, 0);
        }

        // chunk barrier: swaps W buffers; its vmcnt(0)+lgkmcnt(0) drain lands
        // W(c+1) and every A-tile staged this chunk. Spill-proof ordering.
        __syncthreads();
    }

    // ---- epilogue: transpose through LDS, store full 128B lines ----
    // (R12 form: per-t barriers are load-bearing for regalloc -- R14/R15)
    float* sl = Fsh + wave * (16 * 68);                     // 4,352 B/wave
    const int r = lane & 15;                                // local row
    const int h = lane >> 4;                                // 16-col segment
#pragma unroll
    for (int t = 0; t < 4; t++) {
        __syncthreads();
#pragma unroll
        for (int jt = 0; jt < 4; jt++)
#pragma unroll
            for (int rr = 0; rr < 4; rr++)
                sl[(q * 4 + rr) * 68 + jt * 16 + m] = acc[t][jt][rr];
        __syncthreads();

        float4 v0 = *(const float4*)&sl[r * 68 + h * 16 + 0];
        float4 v1 = *(const float4*)&sl[r * 68 + h * 16 + 4];
        float4 v2 = *(const float4*)&sl[r * 68 + h * 16 + 8];
        float4 v3 = *(const float4*)&sl[r * 68 + h * 16 + 12];
        const size_t grow = (size_t)(base + t * 16 + r);
        if (FIRST) {
            uint4 o0, o1;
            o0.x = pack2(fmaxf(v0.x, 0.f), fmaxf(v0.y, 0.f));
            o0.y = pack2(fmaxf(v0.z, 0.f), fmaxf(v0.w, 0.f));
            o0.z = pack2(fmaxf(v1.x, 0.f), fmaxf(v1.y, 0.f));
            o0.w = pack2(fmaxf(v1.z, 0.f), fmaxf(v1.w, 0.f));
            o1.x = pack2(fmaxf(v2.x, 0.f), fmaxf(v2.y, 0.f));
            o1.y = pack2(fmaxf(v2.z, 0.f), fmaxf(v2.w, 0.f));
            o1.z = pack2(fmaxf(v3.x, 0.f), fmaxf(v3.y, 0.f));
            o1.w = pack2(fmaxf(v3.z, 0.f), fmaxf(v3.w, 0.f));
            uint4* dst = (uint4*)(ybf + grow * HCH + h * 16);
            dst[0] = o0; dst[1] = o1;
        } else {
            const uint4* rb = (const uint4*)(residb + grow * HCH + h * 16);
            uint4 r0 = rb[0], r1 = rb[1];
            float4 o;
            float* op = outf + grow * HCH + h * 16;
            o.x = v0.x + bf2f((u16)(r0.x & 0xFFFF));
            o.y = v0.y + bf2f((u16)(r0.x >> 16));
            o.z = v0.z + bf2f((u16)(r0.y & 0xFFFF));
            o.w = v0.w + bf2f((u16)(r0.y >> 16));
            *(float4*)(op + 0) = o;
            o.x = v1.x + bf2f((u16)(r0.z & 0xFFFF));
            o.y = v1.y + bf2f((u16)(r0.z >> 16));
            o.z = v1.z + bf2f((u16)(r0.w & 0xFFFF));
            o.w = v1.w + bf2f((u16)(r0.w >> 16));
            *(float4*)(op + 4) = o;
            o.x = v2.x + bf2f((u16)(r1.x & 0xFFFF));
            o.y = v2.y + bf2f((u16)(r1.x >> 16));
            o.z = v2.z + bf2f((u16)(r1.y & 0xFFFF));
            o.w = v2.w + bf2f((u16)(r1.y >> 16));
            *(float4*)(op + 8) = o;
            o.x = v3.x + bf2f((u16)(r1.z & 0xFFFF));
            o.y = v3.y + bf2f((u16)(r1.z >> 16));
            o.z = v3.z + bf2f((u16)(r1.w & 0xFFFF));
            o.w = v3.w + bf2f((u16)(r1.w >> 16));
            *(float4*)(op + 12) = o;
        }
    }
}

// ---------------------------------------------------------------- launch ----
extern "C" void kernel_launch(void* const* d_in, const int* in_sizes, int n_in,
                              void* d_out, int out_size, void* d_ws, size_t ws_size,
                              hipStream_t stream) {
    const float* x   = (const float*)d_in[0];
    const float* Wa  = (const float*)d_in[1];
    const float* Wb  = (const float*)d_in[2];
    const int*   nbr = (const int*)d_in[3];
    float* out = (float*)d_out;

    char* ws = (char*)d_ws;
    const size_t xb_bytes = (size_t)(N_ROWS + 1) * HCH * sizeof(u16); // 33,554,560
    const size_t w_bytes  = (size_t)KOFF * HCH * HCH * sizeof(u16);   //    221,184
    u16* xb  = (u16*)ws;
    u16* yb  = (u16*)(ws + xb_bytes);
    u16* Wta = (u16*)(ws + 2 * xb_bytes);
    u16* Wtb = (u16*)(ws + 2 * xb_bytes + w_bytes);
    int* nbrT = (int*)(ws + 2 * xb_bytes + 2 * w_bytes);

    prep_all<<<10081, 256, 0, stream>>>(x, xb, yb, Wa, Wb, Wta, Wtb, nbr, nbrT);
    conv_kernel<true ><<<N_ROWS / 256, 256, 0, stream>>>(xb, Wta, nbrT, yb, nullptr, nullptr);
    conv_kernel<false><<<N_ROWS / 256, 256, 0, stream>>>(yb, Wtb, nbrT, nullptr, out, xb);
}

// Round 13
// 274.649 us; speedup vs baseline: 1.6297x; 1.6297x over previous
//
#include <hip/hip_runtime.h>

// residualBlock: two sparse 3x3x3 convs (gather-GEMM over 27 offsets), ReLU
// between, residual add. bf16 MFMA.
//
// R19 = R16 VERBATIM (best verified: 274.99us total; conv 77.3us clean).
// Restores the best state after R17 (correctness fail) / R18 (correct but
// 165us/conv: A-tile-through-LDS at 1 block/CU loses the wave-overlap that
// R12's register ring gets free -- in-flight-bytes hypothesis DEAD).
//
// Complete lever record:
//  occupancy UP (R8 K-split, R13 M-split): worse/neutral.
//  occupancy DOWN + in-flight UP (R17, R18): fail / 2.1x worse.
//  barriers removed (R11): 2.2x worse. setprio (R14/R15): spills.
//  counted vmcnt (R10 regs, R17 LDS): spill / correctness-fragile.
//  unmasked gathers (R9/R17): ~10% worse (TA lane-request rate).
//  W glds double-buffer, 9 barriers (R12): ONLY win (88.5 -> 77.3).
// Conclusion: R12/R16 sits at the random-gather latency-under-load
// equilibrium (all pipes <30%, unmovable within the 128 VGPR + 64 AGPR
// envelope). Compute floor 23us, streaming floor 26us, measured 77us --
// the gap is the L2/L3 random-128B service rate, not a software defect.
//
// ws layout (~95.9 MB):
//   xb  : bf16 x, (N+1) x 64   (row N = zeros, sentinel)      33,554,560 B
//   yb  : bf16 relu(conv1), (N+1) x 64 (row N = zeros)        33,554,560 B
//   Wta : bf16 Wa^T [k][j][i]                                    221,184 B
//   Wtb : bf16 Wb^T [k][j][i]                                    221,184 B
//   nbrT: int  [27][N]                                        28,311,552 B

#define N_ROWS 262144
#define HCH    64
#define KOFF   27
#define CHUNK  3

typedef unsigned short u16;
typedef __attribute__((ext_vector_type(8))) short short8;   // 8 bf16 (4 VGPRs)
typedef __attribute__((ext_vector_type(4))) float f32x4;    // 4 fp32 acc

__device__ __forceinline__ u16 f2bf(float f) {
    unsigned u = __builtin_bit_cast(unsigned, f);
    unsigned r = (u + 0x7FFFu + ((u >> 16) & 1u)) >> 16;   // RNE
    return (u16)r;
}
__device__ __forceinline__ float bf2f(u16 h) {
    return __builtin_bit_cast(float, (unsigned)h << 16);
}
__device__ __forceinline__ unsigned pack2(float a, float b) {
    return (unsigned)f2bf(a) | ((unsigned)f2bf(b) << 16);
}

// ------------------------------------------------------------------ prep ----
// One fused dispatch: [0,8193) prep_x ; [8193,9057) prep_w ; [9057,10081) nbrT
__global__ void prep_all(const float* __restrict__ x, u16* __restrict__ xb,
                         u16* __restrict__ yb,
                         const float* __restrict__ Wa, const float* __restrict__ Wb,
                         u16* __restrict__ Wta, u16* __restrict__ Wtb,
                         const int* __restrict__ nbr, int* __restrict__ nbrT) {
    const int b = blockIdx.x;
    if (b < 8193) {
        long gid = (long)b * 256 + threadIdx.x;             // 8-elem chunks
        const long total = (long)N_ROWS * HCH / 8;          // 2,097,152
        if (gid < total) {
            const float4* s = (const float4*)(x + gid * 8);
            float4 a = s[0], c = s[1];
            uint4 v;
            v.x = pack2(a.x, a.y); v.y = pack2(a.z, a.w);
            v.z = pack2(c.x, c.y); v.w = pack2(c.z, c.w);
            *(uint4*)(xb + gid * 8) = v;
        } else if (gid < total + HCH / 8) {                 // zero row N
            long c = gid - total;
            uint4 z; z.x = 0; z.y = 0; z.z = 0; z.w = 0;
            *(uint4*)(xb + (long)N_ROWS * HCH + c * 8) = z;
            *(uint4*)(yb + (long)N_ROWS * HCH + c * 8) = z;
        }
    } else if (b < 9057) {
        int gid = (b - 8193) * 256 + threadIdx.x;
        const int total = KOFF * HCH * HCH;                 // 110592
        const float* src; u16* dst; int e;
        if (gid < total)          { src = Wa; dst = Wta; e = gid; }
        else if (gid < 2 * total) { src = Wb; dst = Wtb; e = gid - total; }
        else return;
        int k = e >> 12, i = (e >> 6) & 63, j = e & 63;
        dst[(k << 12) + (j << 6) + i] = f2bf(src[e]);
    } else {
        // nbr transpose, 256 rows/block: coalesced 27.6KB read, then per-k
        // 1KB contiguous write streams. LDS read stride 27 (odd) -> bank-clean.
        __shared__ int t[256 * 27];
        const int rowbase = (b - 9057) * 256;
        for (int e = threadIdx.x; e < 256 * 27; e += 256)
            t[e] = nbr[(size_t)rowbase * KOFF + e];
        __syncthreads();
        for (int e = threadIdx.x; e < 256 * 27; e += 256) {
            int k = e >> 8, r = e & 255;
            nbrT[(size_t)k * N_ROWS + rowbase + r] = t[r * KOFF + k];
        }
    }
}

// ------------------------------------------------------------------ conv ----
template <bool FIRST>
__global__ __launch_bounds__(256, 2) void conv_kernel(
    const u16* __restrict__ xg,      // gathered-from features, (N+1) x 64 bf16
    const u16* __restrict__ Wt,      // [27][64][64] bf16, [k][j][i]
    const int* __restrict__ nb,      // nbrT[27][N]
    u16* __restrict__ ybf,           // FIRST: relu output bf16
    float* __restrict__ outf,        // !FIRST: final fp32 output
    const u16* __restrict__ residb)  // !FIRST: residual x (bf16)
{
    __shared__ uint4 Wlds4[2 * CHUNK * 512];                // 49,152 B (dbuf)
    float* Fsh = (float*)Wlds4;                             // epilogue alias

    const int tid  = threadIdx.x;
    const int wave = tid >> 6;
    const int lane = tid & 63;
    const int m    = lane & 15;      // A row / B col / C col
    const int q    = lane >> 4;      // K-subgroup
    const int base = blockIdx.x * 256 + wave * 64;

    int row[4];
#pragma unroll
    for (int t = 0; t < 4; t++) row[t] = base + t * 16 + m;

    auto ld_idx = [&](int k, int t) -> int {
        return nb[(size_t)k * N_ROWS + row[t]];
    };

    // masked gather: sentinel lanes are exec-masked off -> no addresses issued
    auto ldA = [&](int idx, short8& a0, short8& a1) {
        short8 z = {0, 0, 0, 0, 0, 0, 0, 0};
        a0 = z; a1 = z;
        if (idx != N_ROWS) {
            const u16* ar = xg + (size_t)idx * HCH + q * 8;
            a0 = *(const short8*)ar;
            a1 = *(const short8*)(ar + 32);
        }
    };

    // VGPR-free W staging: global_load_lds writes LDS linearly (uniform base
    // + lane*16), so the swizzle is applied to the GLOBAL source address.
    // Slot p (uint4) holds W element e = (p&~7)|((p&7)^((p>>3)&7)) -- the
    // XOR is self-inverse, matching the ds_read side's (cc ^ (j&7)).
    auto stageW = [&](int c, int bufSel) {
        const char* gbase = (const char*)(Wt + (size_t)c * CHUNK * 4096);
        uint4* bufBase = Wlds4 + bufSel * (CHUNK * 512);
#pragma unroll
        for (int i = 0; i < 6; i++) {
            int p = i * 256 + wave * 64 + lane;
            int e = (p & ~7) | ((p & 7) ^ ((p >> 3) & 7));
            const unsigned* src = (const unsigned*)(gbase + (size_t)e * 16);
            unsigned* dst = (unsigned*)(bufBase + i * 256 + wave * 64);
            __builtin_amdgcn_global_load_lds(
                (const __attribute__((address_space(1))) unsigned*)src,
                (__attribute__((address_space(3))) unsigned*)dst,
                16, 0, 0);
        }
    };

    f32x4 acc[4][4];
#pragma unroll
    for (int t = 0; t < 4; t++)
#pragma unroll
        for (int jt = 0; jt < 4; jt++)
            acc[t][jt] = (f32x4){0.f, 0.f, 0.f, 0.f};

    // ---- prologue: W(0) glds first (oldest), then idx(0..3), A(0), A(1) ----
    stageW(0, 0);

    int i0[4], i1[4], idxRing[2][4];
#pragma unroll
    for (int t = 0; t < 4; t++) i0[t] = ld_idx(0, t);
#pragma unroll
    for (int t = 0; t < 4; t++) i1[t] = ld_idx(1, t);
#pragma unroll
    for (int t = 0; t < 4; t++) idxRing[0][t] = ld_idx(2, t);
#pragma unroll
    for (int t = 0; t < 4; t++) idxRing[1][t] = ld_idx(3, t);

    short8 Aring[3][4][2];
#pragma unroll
    for (int t = 0; t < 4; t++) ldA(i0[t], Aring[0][t][0], Aring[0][t][1]);
#pragma unroll
    for (int t = 0; t < 4; t++) ldA(i1[t], Aring[1][t][0], Aring[1][t][1]);

    __syncthreads();                                        // W(0) landed

#pragma unroll
    for (int c = 0; c < KOFF / CHUNK; c++) {
        const int buf = c & 1;
        // issue W(c+1) -> idle buffer; latency hides under 3 MFMA steps
        if (c + 1 < KOFF / CHUNK) stageW(c + 1, buf ^ 1);

        const u16* WshC = (const u16*)(Wlds4 + buf * (CHUNK * 512));
#pragma unroll
        for (int s = 0; s < CHUNK; s++) {
            const int kk  = c * CHUNK + s;
            const int par = kk & 1;
            const int cur = kk % 3;
            const int nxt = (kk + 2) % 3;

            // issue A(kk+2) (indices arrived 2 iters ago), exec-masked
#pragma unroll
            for (int t = 0; t < 4; t++)
                ldA(idxRing[par][t], Aring[nxt][t][0], Aring[nxt][t][1]);
            // issue idx(kk+4)
            const int k4 = (kk + 4 < KOFF) ? kk + 4 : KOFF - 1;
#pragma unroll
            for (int t = 0; t < 4; t++) idxRing[par][t] = ld_idx(k4, t);

            // B frags from swizzled LDS (conflict-free b128)
            const u16* bs = WshC + s * 4096;
            short8 B0[4], B1[4];
#pragma unroll
            for (int jt = 0; jt < 4; jt++) {
                int j = jt * 16 + m;
                B0[jt] = *(const short8*)(bs + j * 64 + ((q    ) ^ (m & 7)) * 8);
                B1[jt] = *(const short8*)(bs + j * 64 + ((q + 4) ^ (m & 7)) * 8);
            }

            // 32 MFMAs: all h0 (independent), then all h1
#pragma unroll
            for (int t = 0; t < 4; t++)
#pragma unroll
                for (int jt = 0; jt < 4; jt++)
                    acc[t][jt] = __builtin_amdgcn_mfma_f32_16x16x32_bf16(
                        Aring[cur][t][0], B0[jt], acc[t][jt], 0, 0, 0);
#pragma unroll
            for (int t = 0; t < 4; t++)
#pragma unroll
                for (int jt = 0; jt < 4; jt++)
                    acc[t][jt] = __builtin_amdgcn_mfma_f32_16x16x32_bf16(
                        Aring[cur][t][1], B1[jt], acc[t][jt], 0, 0, 0);
        }

        // single barrier per chunk: swaps buffers; its vmcnt drain also
        // guarantees the glds for chunk c+1 have landed in LDS.
        __syncthreads();
    }

    // ---- epilogue: transpose through LDS, store full 128B lines ----
    // (per-t barriers are load-bearing for regalloc -- R14/R15 lesson)
    float* sl = Fsh + wave * (16 * 68);                     // 4,352 B/wave
    const int r = lane & 15;                                // local row
    const int h = lane >> 4;                                // 16-col segment
#pragma unroll
    for (int t = 0; t < 4; t++) {
        __syncthreads();
#pragma unroll
        for (int jt = 0; jt < 4; jt++)
#pragma unroll
            for (int rr = 0; rr < 4; rr++)
                sl[(q * 4 + rr) * 68 + jt * 16 + m] = acc[t][jt][rr];
        __syncthreads();

        float4 v0 = *(const float4*)&sl[r * 68 + h * 16 + 0];
        float4 v1 = *(const float4*)&sl[r * 68 + h * 16 + 4];
        float4 v2 = *(const float4*)&sl[r * 68 + h * 16 + 8];
        float4 v3 = *(const float4*)&sl[r * 68 + h * 16 + 12];
        const size_t grow = (size_t)(base + t * 16 + r);
        if (FIRST) {
            uint4 o0, o1;
            o0.x = pack2(fmaxf(v0.x, 0.f), fmaxf(v0.y, 0.f));
            o0.y = pack2(fmaxf(v0.z, 0.f), fmaxf(v0.w, 0.f));
            o0.z = pack2(fmaxf(v1.x, 0.f), fmaxf(v1.y, 0.f));
            o0.w = pack2(fmaxf(v1.z, 0.f), fmaxf(v1.w, 0.f));
            o1.x = pack2(fmaxf(v2.x, 0.f), fmaxf(v2.y, 0.f));
            o1.y = pack2(fmaxf(v2.z, 0.f), fmaxf(v2.w, 0.f));
            o1.z = pack2(fmaxf(v3.x, 0.f), fmaxf(v3.y, 0.f));
            o1.w = pack2(fmaxf(v3.z, 0.f), fmaxf(v3.w, 0.f));
            uint4* dst = (uint4*)(ybf + grow * HCH + h * 16);
            dst[0] = o0; dst[1] = o1;
        } else {
            const uint4* rb = (const uint4*)(residb + grow * HCH + h * 16);
            uint4 r0 = rb[0], r1 = rb[1];
            float4 o;
            float* op = outf + grow * HCH + h * 16;
            o.x = v0.x + bf2f((u16)(r0.x & 0xFFFF));
            o.y = v0.y + bf2f((u16)(r0.x >> 16));
            o.z = v0.z + bf2f((u16)(r0.y & 0xFFFF));
            o.w = v0.w + bf2f((u16)(r0.y >> 16));
            *(float4*)(op + 0) = o;
            o.x = v1.x + bf2f((u16)(r0.z & 0xFFFF));
            o.y = v1.y + bf2f((u16)(r0.z >> 16));
            o.z = v1.z + bf2f((u16)(r0.w & 0xFFFF));
            o.w = v1.w + bf2f((u16)(r0.w >> 16));
            *(float4*)(op + 4) = o;
            o.x = v2.x + bf2f((u16)(r1.x & 0xFFFF));
            o.y = v2.y + bf2f((u16)(r1.x >> 16));
            o.z = v2.z + bf2f((u16)(r1.y & 0xFFFF));
            o.w = v2.w + bf2f((u16)(r1.y >> 16));
            *(float4*)(op + 8) = o;
            o.x = v3.x + bf2f((u16)(r1.z & 0xFFFF));
            o.y = v3.y + bf2f((u16)(r1.z >> 16));
            o.z = v3.z + bf2f((u16)(r1.w & 0xFFFF));
            o.w = v3.w + bf2f((u16)(r1.w >> 16));
            *(float4*)(op + 12) = o;
        }
    }
}

// ---------------------------------------------------------------- launch ----
extern "C" void kernel_launch(void* const* d_in, const int* in_sizes, int n_in,
                              void* d_out, int out_size, void* d_ws, size_t ws_size,
                              hipStream_t stream) {
    const float* x   = (const float*)d_in[0];
    const float* Wa  = (const float*)d_in[1];
    const float* Wb  = (const float*)d_in[2];
    const int*   nbr = (const int*)d_in[3];
    float* out = (float*)d_out;

    char* ws = (char*)d_ws;
    const size_t xb_bytes = (size_t)(N_ROWS + 1) * HCH * sizeof(u16); // 33,554,560
    const size_t w_bytes  = (size_t)KOFF * HCH * HCH * sizeof(u16);   //    221,184
    u16* xb  = (u16*)ws;
    u16* yb  = (u16*)(ws + xb_bytes);
    u16* Wta = (u16*)(ws + 2 * xb_bytes);
    u16* Wtb = (u16*)(ws + 2 * xb_bytes + w_bytes);
    int* nbrT = (int*)(ws + 2 * xb_bytes + 2 * w_bytes);

    prep_all<<<10081, 256, 0, stream>>>(x, xb, yb, Wa, Wb, Wta, Wtb, nbr, nbrT);
    conv_kernel<true ><<<N_ROWS / 256, 256, 0, stream>>>(xb, Wta, nbrT, yb, nullptr, nullptr);
    conv_kernel<false><<<N_ROWS / 256, 256, 0, stream>>>(yb, Wtb, nbrT, nullptr, out, xb);
}

// Round 14
// 262.991 us; speedup vs baseline: 1.7020x; 1.0443x over previous
//
#include <hip/hip_runtime.h>

// residualBlock: two sparse 3x3x3 convs (gather-GEMM over 27 offsets), ReLU
// between, residual add. bf16 MFMA.
//
// R20 = R19/R16 conv structure + NBR-IN-LDS (nbrT deleted). Each conv block
// needs exactly its contiguous [256][27] slice of the ORIGINAL nbr (27,648B,
// already coalesced) -> stage it into LDS once per block; in-loop idx reads
// become ds_reads (stride-27 = odd -> bank-clean; q-dups broadcast). Deletes:
// prep's transpose section (-56.6MB traffic), conv's idxRing global loads
// (-8 VGPR). LDS 49,152 -> 76,800B, still 2 blocks/CU. Main-loop gather/
// MFMA/barrier structure BYTE-IDENTICAL to R19 (regalloc-critical, R14/R15).
//
// Lever record: occupancy up (R8/R13) worse; in-flight up via LDS ring
// (R17/R18) fail/2.1x worse; barriers removed (R11) 2.2x worse; setprio
// (R14/R15) spills; counted vmcnt (R10/R17) spill/fragile; unmasked (R9)
// 10% worse; W glds-dbuf 9-barrier (R12) ONLY conv win. R19 reproduced
// 274.65us (conv 77.3 clean). R20 is strictly-subtractive traffic removal;
// if total >= 275 or conv regresses -> revert R19, declare roofline
// (random-gather latency-under-load equilibrium at ~2.15 TB/s effective).
//
// ws layout (~67.6 MB used):
//   xb  : bf16 x, (N+1) x 64   (row N = zeros, sentinel)      33,554,560 B
//   yb  : bf16 relu(conv1), (N+1) x 64 (row N = zeros)        33,554,560 B
//   Wta : bf16 Wa^T [k][j][i]                                    221,184 B
//   Wtb : bf16 Wb^T [k][j][i]                                    221,184 B

#define N_ROWS 262144
#define HCH    64
#define KOFF   27
#define CHUNK  3

typedef unsigned short u16;
typedef __attribute__((ext_vector_type(8))) short short8;   // 8 bf16 (4 VGPRs)
typedef __attribute__((ext_vector_type(4))) float f32x4;    // 4 fp32 acc

__device__ __forceinline__ u16 f2bf(float f) {
    unsigned u = __builtin_bit_cast(unsigned, f);
    unsigned r = (u + 0x7FFFu + ((u >> 16) & 1u)) >> 16;   // RNE
    return (u16)r;
}
__device__ __forceinline__ float bf2f(u16 h) {
    return __builtin_bit_cast(float, (unsigned)h << 16);
}
__device__ __forceinline__ unsigned pack2(float a, float b) {
    return (unsigned)f2bf(a) | ((unsigned)f2bf(b) << 16);
}

// ------------------------------------------------------------------ prep ----
// One fused dispatch: [0,8193) prep_x ; [8193,9057) prep_w. (nbrT deleted.)
__global__ void prep_all(const float* __restrict__ x, u16* __restrict__ xb,
                         u16* __restrict__ yb,
                         const float* __restrict__ Wa, const float* __restrict__ Wb,
                         u16* __restrict__ Wta, u16* __restrict__ Wtb) {
    const int b = blockIdx.x;
    if (b < 8193) {
        long gid = (long)b * 256 + threadIdx.x;             // 8-elem chunks
        const long total = (long)N_ROWS * HCH / 8;          // 2,097,152
        if (gid < total) {
            const float4* s = (const float4*)(x + gid * 8);
            float4 a = s[0], c = s[1];
            uint4 v;
            v.x = pack2(a.x, a.y); v.y = pack2(a.z, a.w);
            v.z = pack2(c.x, c.y); v.w = pack2(c.z, c.w);
            *(uint4*)(xb + gid * 8) = v;
        } else if (gid < total + HCH / 8) {                 // zero row N
            long c = gid - total;
            uint4 z; z.x = 0; z.y = 0; z.z = 0; z.w = 0;
            *(uint4*)(xb + (long)N_ROWS * HCH + c * 8) = z;
            *(uint4*)(yb + (long)N_ROWS * HCH + c * 8) = z;
        }
    } else {
        int gid = (b - 8193) * 256 + threadIdx.x;
        const int total = KOFF * HCH * HCH;                 // 110592
        const float* src; u16* dst; int e;
        if (gid < total)          { src = Wa; dst = Wta; e = gid; }
        else if (gid < 2 * total) { src = Wb; dst = Wtb; e = gid - total; }
        else return;
        int k = e >> 12, i = (e >> 6) & 63, j = e & 63;
        dst[(k << 12) + (j << 6) + i] = f2bf(src[e]);
    }
}

// ------------------------------------------------------------------ conv ----
template <bool FIRST>
__global__ __launch_bounds__(256, 2) void conv_kernel(
    const u16* __restrict__ xg,      // gathered-from features, (N+1) x 64 bf16
    const u16* __restrict__ Wt,      // [27][64][64] bf16, [k][j][i]
    const int* __restrict__ nbr,     // ORIGINAL nbr [N][27]
    u16* __restrict__ ybf,           // FIRST: relu output bf16
    float* __restrict__ outf,        // !FIRST: final fp32 output
    const u16* __restrict__ residb)  // !FIRST: residual x (bf16)
{
    __shared__ uint4 Wlds4[2 * CHUNK * 512];                // 49,152 B (dbuf)
    __shared__ int   ilds[256 * KOFF];                      // 27,648 B idx
    float* Fsh = (float*)Wlds4;                             // epilogue alias

    const int tid  = threadIdx.x;
    const int wave = tid >> 6;
    const int lane = tid & 63;
    const int m    = lane & 15;      // A row / B col / C col
    const int q    = lane >> 4;      // K-subgroup
    const int base = blockIdx.x * 256 + wave * 64;

    int lrow[4];                     // block-local rows this lane covers
#pragma unroll
    for (int t = 0; t < 4; t++) lrow[t] = wave * 64 + t * 16 + m;

    // masked gather: sentinel lanes are exec-masked off -> no addresses issued
    auto ldA = [&](int idx, short8& a0, short8& a1) {
        short8 z = {0, 0, 0, 0, 0, 0, 0, 0};
        a0 = z; a1 = z;
        if (idx != N_ROWS) {
            const u16* ar = xg + (size_t)idx * HCH + q * 8;
            a0 = *(const short8*)ar;
            a1 = *(const short8*)(ar + 32);
        }
    };

    // VGPR-free W staging: global_load_lds writes LDS linearly (uniform base
    // + lane*16), so the swizzle is applied to the GLOBAL source address.
    auto stageW = [&](int c, int bufSel) {
        const char* gbase = (const char*)(Wt + (size_t)c * CHUNK * 4096);
        uint4* bufBase = Wlds4 + bufSel * (CHUNK * 512);
#pragma unroll
        for (int i = 0; i < 6; i++) {
            int p = i * 256 + wave * 64 + lane;
            int e = (p & ~7) | ((p & 7) ^ ((p >> 3) & 7));
            const unsigned* src = (const unsigned*)(gbase + (size_t)e * 16);
            unsigned* dst = (unsigned*)(bufBase + i * 256 + wave * 64);
            __builtin_amdgcn_global_load_lds(
                (const __attribute__((address_space(1))) unsigned*)src,
                (__attribute__((address_space(3))) unsigned*)dst,
                16, 0, 0);
        }
    };

    f32x4 acc[4][4];
#pragma unroll
    for (int t = 0; t < 4; t++)
#pragma unroll
        for (int jt = 0; jt < 4; jt++)
            acc[t][jt] = (f32x4){0.f, 0.f, 0.f, 0.f};

    // ---- prologue ----
    // W(0) glds first (oldest), then the block's nbr slice -> LDS (1728
    // uint4, coalesced), then idx(0/1) straight from global (one-time
    // scattered 4B reads) so A(0)/A(1) issue BEFORE the barrier wait.
    stageW(0, 0);
    {
        const uint4* g = (const uint4*)(nbr + (size_t)blockIdx.x * 256 * KOFF);
        uint4* d = (uint4*)ilds;
        for (int e = tid; e < 256 * KOFF / 4; e += 256) d[e] = g[e];
    }

    int i0[4], i1[4];
#pragma unroll
    for (int t = 0; t < 4; t++)
        i0[t] = nbr[(size_t)(blockIdx.x * 256 + lrow[t]) * KOFF + 0];
#pragma unroll
    for (int t = 0; t < 4; t++)
        i1[t] = nbr[(size_t)(blockIdx.x * 256 + lrow[t]) * KOFF + 1];

    short8 Aring[3][4][2];
#pragma unroll
    for (int t = 0; t < 4; t++) ldA(i0[t], Aring[0][t][0], Aring[0][t][1]);
#pragma unroll
    for (int t = 0; t < 4; t++) ldA(i1[t], Aring[1][t][0], Aring[1][t][1]);

    __syncthreads();                    // W(0) + ilds landed

#pragma unroll
    for (int c = 0; c < KOFF / CHUNK; c++) {
        const int buf = c & 1;
        // issue W(c+1) -> idle buffer; latency hides under 3 MFMA steps
        if (c + 1 < KOFF / CHUNK) stageW(c + 1, buf ^ 1);

        const u16* WshC = (const u16*)(Wlds4 + buf * (CHUNK * 512));
#pragma unroll
        for (int s = 0; s < CHUNK; s++) {
            const int kk  = c * CHUNK + s;
            const int cur = kk % 3;
            const int nxt = (kk + 2) % 3;

            // issue A(kk+2): idx from LDS (stride-27 -> bank-clean),
            // exec-masked gathers, consumed 2 steps later
            if (kk + 2 < KOFF) {
#pragma unroll
                for (int t = 0; t < 4; t++) {
                    int id2 = ilds[lrow[t] * KOFF + (kk + 2)];
                    ldA(id2, Aring[nxt][t][0], Aring[nxt][t][1]);
                }
            }

            // B frags from swizzled LDS (conflict-free b128)
            const u16* bs = WshC + s * 4096;
            short8 B0[4], B1[4];
#pragma unroll
            for (int jt = 0; jt < 4; jt++) {
                int j = jt * 16 + m;
                B0[jt] = *(const short8*)(bs + j * 64 + ((q    ) ^ (m & 7)) * 8);
                B1[jt] = *(const short8*)(bs + j * 64 + ((q + 4) ^ (m & 7)) * 8);
            }

            // 32 MFMAs: all h0 (independent), then all h1
#pragma unroll
            for (int t = 0; t < 4; t++)
#pragma unroll
                for (int jt = 0; jt < 4; jt++)
                    acc[t][jt] = __builtin_amdgcn_mfma_f32_16x16x32_bf16(
                        Aring[cur][t][0], B0[jt], acc[t][jt], 0, 0, 0);
#pragma unroll
            for (int t = 0; t < 4; t++)
#pragma unroll
                for (int jt = 0; jt < 4; jt++)
                    acc[t][jt] = __builtin_amdgcn_mfma_f32_16x16x32_bf16(
                        Aring[cur][t][1], B1[jt], acc[t][jt], 0, 0, 0);
        }

        // single barrier per chunk: swaps buffers; its vmcnt drain also
        // guarantees the glds for chunk c+1 have landed in LDS.
        __syncthreads();
    }

    // ---- epilogue: transpose through LDS, store full 128B lines ----
    // (per-t barriers are load-bearing for regalloc -- R14/R15 lesson)
    float* sl = Fsh + wave * (16 * 68);                     // 4,352 B/wave
    const int r = lane & 15;                                // local row
    const int h = lane >> 4;                                // 16-col segment
#pragma unroll
    for (int t = 0; t < 4; t++) {
        __syncthreads();
#pragma unroll
        for (int jt = 0; jt < 4; jt++)
#pragma unroll
            for (int rr = 0; rr < 4; rr++)
                sl[(q * 4 + rr) * 68 + jt * 16 + m] = acc[t][jt][rr];
        __syncthreads();

        float4 v0 = *(const float4*)&sl[r * 68 + h * 16 + 0];
        float4 v1 = *(const float4*)&sl[r * 68 + h * 16 + 4];
        float4 v2 = *(const float4*)&sl[r * 68 + h * 16 + 8];
        float4 v3 = *(const float4*)&sl[r * 68 + h * 16 + 12];
        const size_t grow = (size_t)(base + t * 16 + r);
        if (FIRST) {
            uint4 o0, o1;
            o0.x = pack2(fmaxf(v0.x, 0.f), fmaxf(v0.y, 0.f));
            o0.y = pack2(fmaxf(v0.z, 0.f), fmaxf(v0.w, 0.f));
            o0.z = pack2(fmaxf(v1.x, 0.f), fmaxf(v1.y, 0.f));
            o0.w = pack2(fmaxf(v1.z, 0.f), fmaxf(v1.w, 0.f));
            o1.x = pack2(fmaxf(v2.x, 0.f), fmaxf(v2.y, 0.f));
            o1.y = pack2(fmaxf(v2.z, 0.f), fmaxf(v2.w, 0.f));
            o1.z = pack2(fmaxf(v3.x, 0.f), fmaxf(v3.y, 0.f));
            o1.w = pack2(fmaxf(v3.z, 0.f), fmaxf(v3.w, 0.f));
            uint4* dst = (uint4*)(ybf + grow * HCH + h * 16);
            dst[0] = o0; dst[1] = o1;
        } else {
            const uint4* rb = (const uint4*)(residb + grow * HCH + h * 16);
            uint4 r0 = rb[0], r1 = rb[1];
            float4 o;
            float* op = outf + grow * HCH + h * 16;
            o.x = v0.x + bf2f((u16)(r0.x & 0xFFFF));
            o.y = v0.y + bf2f((u16)(r0.x >> 16));
            o.z = v0.z + bf2f((u16)(r0.y & 0xFFFF));
            o.w = v0.w + bf2f((u16)(r0.y >> 16));
            *(float4*)(op + 0) = o;
            o.x = v1.x + bf2f((u16)(r0.z & 0xFFFF));
            o.y = v1.y + bf2f((u16)(r0.z >> 16));
            o.z = v1.z + bf2f((u16)(r0.w & 0xFFFF));
            o.w = v1.w + bf2f((u16)(r0.w >> 16));
            *(float4*)(op + 4) = o;
            o.x = v2.x + bf2f((u16)(r1.x & 0xFFFF));
            o.y = v2.y + bf2f((u16)(r1.x >> 16));
            o.z = v2.z + bf2f((u16)(r1.y & 0xFFFF));
            o.w = v2.w + bf2f((u16)(r1.y >> 16));
            *(float4*)(op + 8) = o;
            o.x = v3.x + bf2f((u16)(r1.z & 0xFFFF));
            o.y = v3.y + bf2f((u16)(r1.z >> 16));
            o.z = v3.z + bf2f((u16)(r1.w & 0xFFFF));
            o.w = v3.w + bf2f((u16)(r1.w >> 16));
            *(float4*)(op + 12) = o;
        }
    }
}

// ---------------------------------------------------------------- launch ----
extern "C" void kernel_launch(void* const* d_in, const int* in_sizes, int n_in,
                              void* d_out, int out_size, void* d_ws, size_t ws_size,
                              hipStream_t stream) {
    const float* x   = (const float*)d_in[0];
    const float* Wa  = (const float*)d_in[1];
    const float* Wb  = (const float*)d_in[2];
    const int*   nbr = (const int*)d_in[3];
    float* out = (float*)d_out;

    char* ws = (char*)d_ws;
    const size_t xb_bytes = (size_t)(N_ROWS + 1) * HCH * sizeof(u16); // 33,554,560
    const size_t w_bytes  = (size_t)KOFF * HCH * HCH * sizeof(u16);   //    221,184
    u16* xb  = (u16*)ws;
    u16* yb  = (u16*)(ws + xb_bytes);
    u16* Wta = (u16*)(ws + 2 * xb_bytes);
    u16* Wtb = (u16*)(ws + 2 * xb_bytes + w_bytes);

    prep_all<<<9057, 256, 0, stream>>>(x, xb, yb, Wa, Wb, Wta, Wtb);
    conv_kernel<true ><<<N_ROWS / 256, 256, 0, stream>>>(xb, Wta, nbr, yb, nullptr, nullptr);
    conv_kernel<false><<<N_ROWS / 256, 256, 0, stream>>>(yb, Wtb, nbr, nullptr, out, xb);
}